// Round 4
// baseline (390.846 us; speedup 1.0000x reference)
//
#include <hip/hip_runtime.h>
#include <cstddef>

namespace {

constexpr int kB   = 4096;
constexpr int kT   = 1024;
constexpr int kI   = 8;
constexpr int kH   = 12;
constexpr int kA   = 4;
constexpr int kTC  = 32;               // timesteps per staged chunk
constexpr int kNCH = kT / kTC;         // 32 chunks
constexpr int kXRow  = kTC * kI + 8;   // 264 floats per element chunk region (pad: bank offset)
constexpr int kWaveX = 2 * kXRow;      // 528 floats per wave (2 elements)
constexpr int kBlkX  = 4 * kWaveX;     // 2112 floats per buffer (4 waves)

__device__ __forceinline__ float bperm(int byte_addr, float v) {
    return __int_as_float(__builtin_amdgcn_ds_bpermute(byte_addr, __float_as_int(v)));
}

__global__ __launch_bounds__(256, 2)
void lstm_fused_kernel(const float* __restrict__ x,
                       const float* __restrict__ W_ih,
                       const float* __restrict__ W_hh,
                       const float* __restrict__ b_ih,
                       const float* __restrict__ b_hh,
                       const float* __restrict__ W_fc,
                       const float* __restrict__ b_fc,
                       float* __restrict__ out) {
    __shared__ float xs[2][kBlkX];     // staged x, double-buffered, wave-private regions

    const int tid = threadIdx.x;
    const int wv  = tid >> 6;          // wave id in block
    const int l64 = tid & 63;          // lane in wave
    const int h32 = (l64 >> 5) & 1;    // element half within wave
    const int s   = l64 & 31;          // lane within element
    const int r   = s & 15;
    const int g16 = s >> 4;            // 0: i/f rows (+FC), 1: g/o rows
    const int hrow = (r < kH) ? r : (kH - 1);
    const bool isFC = (g16 == 0) && (r >= kH);
    const int a = isFC ? (r - kH) : 0;
    const int b = blockIdx.x * 8 + wv * 2 + h32;   // batch element

    // ---- per-lane weight rows (PyTorch gate order i,f,g,o) ----
    const int row1 = (g16 == 0) ? (0 * kH + hrow) : (2 * kH + hrow);  // i or g
    const int row2 = (g16 == 0) ? (1 * kH + hrow) : (3 * kH + hrow);  // f or o
    float w1h[12], w2h[12], w1x[8], w2x[8];
#pragma unroll
    for (int k = 0; k < 12; ++k) { w1h[k] = W_hh[row1 * kH + k]; w2h[k] = W_hh[row2 * kH + k]; }
#pragma unroll
    for (int i = 0; i < 8; ++i)  { w1x[i] = W_ih[row1 * kI + i]; w2x[i] = W_ih[row2 * kI + i]; }
    float wb1 = b_ih[row1] + b_hh[row1];
    float wb2 = b_ih[row2] + b_hh[row2];
    if (isFC) {   // fold FC into dot1: W_fc row over h, no x-part, bias = b_fc
#pragma unroll
        for (int k = 0; k < 12; ++k) w1h[k] = W_fc[a * kH + k];
#pragma unroll
        for (int i = 0; i < 8; ++i)  w1x[i] = 0.0f;
        wb1 = b_fc[a];
    }
    // act1 constants: sigmoid for i-rows, tanh (=2*sig(2v)-1) for g-rows
    const float c1 = (g16 == 0) ? -1.442695041f : -2.885390082f;
    const float m1 = (g16 == 0) ? 1.0f : 2.0f;
    const float a1 = (g16 == 0) ? 0.0f : -1.0f;

    // bpermute addresses (bytes of lane index within wave)
    const int ebase = (l64 & 32) << 2;                 // this element's lane 0
    const int gaddr = ebase + ((16 + hrow) << 2);      // pull g/o from lane +16

    // ---- x staging addressing ----
    const float* xg = x + (size_t)b * (kT * kI);       // this element's x base
    const int sw = wv * kWaveX + h32 * kXRow;          // float offset of elem region in xs

    float4 xp0, xp1;
    {   // prologue: stage chunk 0 into buffer 0
        const float4* gp = (const float4*)xg;
        const float4 ra = gp[s];
        const float4 rb = gp[s + 32];
        *(float4*)&xs[0][sw + s * 4]       = ra;
        *(float4*)&xs[0][sw + s * 4 + 128] = rb;
        asm volatile("s_waitcnt lgkmcnt(0)" ::: "memory");
        __builtin_amdgcn_sched_barrier(0);
        xp0 = *(const float4*)&xs[0][sw];
        xp1 = *(const float4*)&xs[0][sw + 4];
    }

    float h = 0.0f, cst = 0.0f;
    float hall[12];
#pragma unroll
    for (int k = 0; k < 12; ++k) hall[k] = 0.0f;

    float* op = out + (size_t)b * (kT * kA) + a;   // moving output ptr (FC lanes)

    int cb = 0;
#pragma unroll 1
    for (int ch = 0; ch < kNCH; ++ch) {
        float4 ra, rb;
        if (ch + 1 < kNCH) {   // issue next chunk's global loads early
            const float4* gp = (const float4*)(xg + (size_t)(ch + 1) * (kTC * kI));
            ra = gp[s];
            rb = gp[s + 32];
        }
#pragma unroll 2
        for (int tt = 0; tt < kTC; ++tt) {
            // dual dot: gates (and FC on lanes 12-15, one step delayed)
            float s1 = wb1, s2 = wb2;
#pragma unroll
            for (int k = 0; k < 12; ++k) {
                s1 = fmaf(w1h[k], hall[k], s1);
                s2 = fmaf(w2h[k], hall[k], s2);
            }
            const float xv[8] = {xp0.x, xp0.y, xp0.z, xp0.w, xp1.x, xp1.y, xp1.z, xp1.w};
#pragma unroll
            for (int i = 0; i < 8; ++i) {
                s1 = fmaf(w1x[i], xv[i], s1);
                s2 = fmaf(w2x[i], xv[i], s2);
            }
            // prefetch next step's x (off critical path)
            if (tt + 1 < kTC) {
                xp0 = *(const float4*)&xs[cb][sw + (tt + 1) * 8];
                xp1 = *(const float4*)&xs[cb][sw + (tt + 1) * 8 + 4];
            }
            // FC store: s1 on FC lanes = wfc . h_{t-1} + b_fc = out_{t-1}
            if ((ch | tt) != 0) {
                if (isFC) op[-kA] = s1;
            }
            // activations (uniform path via per-lane constants)
            const float e1   = __builtin_amdgcn_exp2f(c1 * s1);
            const float act1 = fmaf(m1, __builtin_amdgcn_rcpf(1.0f + e1), a1);  // sig(i) | tanh(g)
            const float e2   = __builtin_amdgcn_exp2f(-1.442695041f * s2);
            const float act2 = __builtin_amdgcn_rcpf(1.0f + e2);                // sig(f) | sig(o)
            // gather g,o from lane +16
            const float gv = bperm(gaddr, act1);
            const float ov = bperm(gaddr, act2);
            // state update (meaningful on lanes s<12)
            cst = fmaf(act2, cst, act1 * gv);           // c = f*c + i*g
            const float ec = __builtin_amdgcn_exp2f(-2.885390082f * cst);
            const float tc = fmaf(2.0f, __builtin_amdgcn_rcpf(1.0f + ec), -1.0f);
            h = ov * tc;                                 // h = o * tanh(c)
            // broadcast h_t to all 32 lanes of the element
#pragma unroll
            for (int k = 0; k < 12; ++k) hall[k] = bperm(ebase + (k << 2), h);
            op += kA;
        }
        if (ch + 1 < kNCH) {   // late LDS write of prefetched chunk + fence
            const int nb = cb ^ 1;
            *(float4*)&xs[nb][sw + s * 4]       = ra;
            *(float4*)&xs[nb][sw + s * 4 + 128] = rb;
            asm volatile("s_waitcnt lgkmcnt(0)" ::: "memory");
            __builtin_amdgcn_sched_barrier(0);
            xp0 = *(const float4*)&xs[nb][sw];
            xp1 = *(const float4*)&xs[nb][sw + 4];
            cb = nb;
        }
    }

    // epilogue: out[T-1] = wfc . h_{T-1} + b_fc
    {
        float s1 = wb1;
#pragma unroll
        for (int k = 0; k < 12; ++k) s1 = fmaf(w1h[k], hall[k], s1);
        if (isFC) op[-kA] = s1;
    }
    // hn, cn (shapes [1,B,12] each), concatenated after out
    if (s < kH) {
        float* hn = out + (size_t)kB * kT * kA;
        hn[(size_t)b * kH + s] = h;
        hn[(size_t)kB * kH + (size_t)b * kH + s] = cst;
    }
}

}  // namespace

extern "C" void kernel_launch(void* const* d_in, const int* in_sizes, int n_in,
                              void* d_out, int out_size, void* d_ws, size_t ws_size,
                              hipStream_t stream) {
    (void)in_sizes; (void)n_in; (void)d_ws; (void)ws_size; (void)out_size;
    const float* x    = (const float*)d_in[0];
    const float* W_ih = (const float*)d_in[1];
    const float* W_hh = (const float*)d_in[2];
    const float* b_ih = (const float*)d_in[3];
    const float* b_hh = (const float*)d_in[4];
    const float* W_fc = (const float*)d_in[5];
    const float* b_fc = (const float*)d_in[6];
    float* out = (float*)d_out;
    hipLaunchKernelGGL(lstm_fused_kernel, dim3(kB / 8), dim3(256), 0, stream,
                       x, W_ih, W_hh, b_ih, b_hh, W_fc, b_fc, out);
}

// Round 5
// 352.468 us; speedup vs baseline: 1.1089x; 1.1089x over previous
//
#include <hip/hip_runtime.h>
#include <cstddef>

namespace {

constexpr int kB   = 4096;
constexpr int kT   = 1024;
constexpr int kI   = 8;
constexpr int kH   = 12;
constexpr int kA   = 4;
constexpr int kTC  = 32;               // timesteps per staged chunk
constexpr int kNCH = kT / kTC;         // 32 chunks
constexpr int kXRow  = kTC * kI + 8;   // 264 floats per element region (pad spreads banks)
constexpr int kWaveX = 4 * kXRow;      // 1056 floats per wave (4 elements)
constexpr int kBlkX  = 4 * kWaveX;     // 4224 floats per buffer (4 waves)

constexpr float kL2E  = 1.442695041f;  // log2(e)
constexpr float kL2E2 = 2.885390082f;  // 2*log2(e)

// DPP row_ror:N within 16-lane rows — VALU pipe, no LDS traffic.
template<int N>
__device__ __forceinline__ float ror16(float v) {
    return __int_as_float(__builtin_amdgcn_mov_dpp(__float_as_int(v), 0x120 + N, 0xF, 0xF, false));
}

__global__ __launch_bounds__(256, 1)
void lstm_fused_kernel(const float* __restrict__ x,
                       const float* __restrict__ W_ih,
                       const float* __restrict__ W_hh,
                       const float* __restrict__ b_ih,
                       const float* __restrict__ b_hh,
                       const float* __restrict__ W_fc,
                       const float* __restrict__ b_fc,
                       float* __restrict__ out) {
    __shared__ float xs[2][kBlkX];     // staged x, double-buffered, wave-private regions

    const int tid = threadIdx.x;
    const int wv  = tid >> 6;          // wave in block
    const int l64 = tid & 63;          // lane in wave
    const int grp = l64 >> 4;          // 16-lane group == DPP row == element
    const int j   = l64 & 15;          // lane within group
    const int b   = blockIdx.x * 16 + wv * 4 + grp;   // batch element
    const bool isFC = (j >= kH);
    const int a = isFC ? (j - kH) : 0;

    // Runtime-probe the row_ror direction so the sign convention can't bite:
    // probe = lane (j + dir) & 15 for ror:1.
    const int probe = __builtin_amdgcn_mov_dpp(j, 0x121, 0xF, 0xF, false);
    const int dir = (probe - j) & 15;  // 1 or 15 (== -1 mod 16), wave-uniform

    // ---- per-lane weights, h-columns PRE-ROTATED to match the DPP gather ----
    // hr[k] will hold h of lane (j + dir*k)&15, so wh[g][k] = W[row_g][(j+dir*k)&15].
    float wh[4][16], wx[4][8], bs[4];
    if (!isFC) {
#pragma unroll
        for (int g = 0; g < 4; ++g) {              // PyTorch gate order i,f,g,o
            const int r = g * kH + j;
#pragma unroll
            for (int k = 0; k < 16; ++k) {
                const int col = (j + dir * k) & 15;
                wh[g][k] = (col < kH) ? W_hh[r * kH + col] : 0.0f;
            }
#pragma unroll
            for (int i = 0; i < 8; ++i) wx[g][i] = W_ih[r * kI + i];
            bs[g] = b_ih[r] + b_hh[r];
        }
    } else {                                       // FC folded into "gate 0", no x-part
#pragma unroll
        for (int k = 0; k < 16; ++k) {
            const int col = (j + dir * k) & 15;
            wh[0][k] = (col < kH) ? W_fc[a * kH + col] : 0.0f;
        }
#pragma unroll
        for (int g = 1; g < 4; ++g)
#pragma unroll
            for (int k = 0; k < 16; ++k) wh[g][k] = 0.0f;
#pragma unroll
        for (int g = 0; g < 4; ++g)
#pragma unroll
            for (int i = 0; i < 8; ++i) wx[g][i] = 0.0f;
        bs[0] = b_fc[a]; bs[1] = 0.0f; bs[2] = 0.0f; bs[3] = 0.0f;
        // note: on FC lanes s2==0 -> g=tanh(0)=0 -> c stays 0 -> h stays 0 exactly,
        // so rotated-in values from lanes 12..15 are 0 (and their weights are 0 too).
    }

    // ---- x staging (wave-private, fence-ordered; pattern proven in r3/r4) ----
    const float* xg = x + (size_t)b * (kT * kI);
    const int sbase = wv * kWaveX + grp * kXRow;

    float4 rv0, rv1, rv2, rv3;
    {   // prologue: stage chunk 0 into buffer 0 (each group stages its own element)
        const float4* gp = (const float4*)xg;
        rv0 = gp[j]; rv1 = gp[16 + j]; rv2 = gp[32 + j]; rv3 = gp[48 + j];
        *(float4*)&xs[0][sbase + j * 4]        = rv0;
        *(float4*)&xs[0][sbase + (16 + j) * 4] = rv1;
        *(float4*)&xs[0][sbase + (32 + j) * 4] = rv2;
        *(float4*)&xs[0][sbase + (48 + j) * 4] = rv3;
    }
    asm volatile("s_waitcnt lgkmcnt(0)" ::: "memory");
    __builtin_amdgcn_sched_barrier(0);
    float4 xp0 = *(const float4*)&xs[0][sbase];
    float4 xp1 = *(const float4*)&xs[0][sbase + 4];

    float h = 0.0f, c = 0.0f;
    float hr[16];
#pragma unroll
    for (int k = 0; k < 16; ++k) hr[k] = 0.0f;

    float* op = out + (size_t)b * (kT * kA) + a;   // moving FC output ptr

    int cb = 0;
#pragma unroll 1
    for (int ch = 0; ch < kNCH; ++ch) {
        if (ch + 1 < kNCH) {   // issue next chunk's global loads early
            const float4* gp = (const float4*)(xg + (size_t)(ch + 1) * (kTC * kI));
            rv0 = gp[j]; rv1 = gp[16 + j]; rv2 = gp[32 + j]; rv3 = gp[48 + j];
        }
#pragma unroll 2
        for (int tt = 0; tt < kTC; ++tt) {
            // 4 gate dots over rotated h (16, zero-padded) then x (8)
            float s0 = bs[0], s1 = bs[1], s2 = bs[2], s3 = bs[3];
#pragma unroll
            for (int k = 0; k < 16; ++k) {
                s0 = fmaf(wh[0][k], hr[k], s0);
                s1 = fmaf(wh[1][k], hr[k], s1);
                s2 = fmaf(wh[2][k], hr[k], s2);
                s3 = fmaf(wh[3][k], hr[k], s3);
            }
            const float xv[8] = {xp0.x, xp0.y, xp0.z, xp0.w, xp1.x, xp1.y, xp1.z, xp1.w};
#pragma unroll
            for (int i = 0; i < 8; ++i) {
                s0 = fmaf(wx[0][i], xv[i], s0);
                s1 = fmaf(wx[1][i], xv[i], s1);
                s2 = fmaf(wx[2][i], xv[i], s2);
                s3 = fmaf(wx[3][i], xv[i], s3);
            }
            // prefetch next step's x (broadcast read, off critical path)
            if (tt + 1 < kTC) {
                xp0 = *(const float4*)&xs[cb][sbase + (tt + 1) * 8];
                xp1 = *(const float4*)&xs[cb][sbase + (tt + 1) * 8 + 4];
            }
            // FC lanes: s0 = wfc.h_{t-1} + b_fc = out[t-1] (one-step delay)
            if ((ch | tt) != 0) { if (isFC) op[-kA] = s0; }
            // activations
            const float e0 = __builtin_amdgcn_exp2f(-kL2E  * s0);
            const float iv = __builtin_amdgcn_rcpf(1.0f + e0);
            const float e1 = __builtin_amdgcn_exp2f(-kL2E  * s1);
            const float fv = __builtin_amdgcn_rcpf(1.0f + e1);
            const float e2 = __builtin_amdgcn_exp2f(-kL2E2 * s2);
            const float gv = fmaf(2.0f, __builtin_amdgcn_rcpf(1.0f + e2), -1.0f);
            const float e3 = __builtin_amdgcn_exp2f(-kL2E  * s3);
            const float ov = __builtin_amdgcn_rcpf(1.0f + e3);
            // state update
            c = fmaf(fv, c, iv * gv);
            const float ec = __builtin_amdgcn_exp2f(-kL2E2 * c);
            const float tc = fmaf(2.0f, __builtin_amdgcn_rcpf(1.0f + ec), -1.0f);
            h = ov * tc;
            // all-gather h within the 16-lane row: pure VALU, no LDS pipe
            hr[0]  = h;
            hr[1]  = ror16<1>(h);
            hr[2]  = ror16<2>(h);
            hr[3]  = ror16<3>(h);
            hr[4]  = ror16<4>(h);
            hr[5]  = ror16<5>(h);
            hr[6]  = ror16<6>(h);
            hr[7]  = ror16<7>(h);
            hr[8]  = ror16<8>(h);
            hr[9]  = ror16<9>(h);
            hr[10] = ror16<10>(h);
            hr[11] = ror16<11>(h);
            hr[12] = ror16<12>(h);
            hr[13] = ror16<13>(h);
            hr[14] = ror16<14>(h);
            hr[15] = ror16<15>(h);
            op += kA;
        }
        if (ch + 1 < kNCH) {   // late LDS write of prefetched chunk + fence
            const int nb = cb ^ 1;
            *(float4*)&xs[nb][sbase + j * 4]        = rv0;
            *(float4*)&xs[nb][sbase + (16 + j) * 4] = rv1;
            *(float4*)&xs[nb][sbase + (32 + j) * 4] = rv2;
            *(float4*)&xs[nb][sbase + (48 + j) * 4] = rv3;
            asm volatile("s_waitcnt lgkmcnt(0)" ::: "memory");
            __builtin_amdgcn_sched_barrier(0);
            xp0 = *(const float4*)&xs[nb][sbase];
            xp1 = *(const float4*)&xs[nb][sbase + 4];
            cb = nb;
        }
    }

    {   // epilogue: out[T-1] = wfc . h_{T-1} + b_fc
        float s0 = bs[0];
#pragma unroll
        for (int k = 0; k < 16; ++k) s0 = fmaf(wh[0][k], hr[k], s0);
        if (isFC) op[-kA] = s0;
    }
    if (!isFC) {   // hn, cn (shapes [1,B,12] each), concatenated after out
        float* hn = out + (size_t)kB * kT * kA;
        hn[(size_t)b * kH + j] = h;
        hn[(size_t)kB * kH + (size_t)b * kH + j] = c;
    }
}

}  // namespace

extern "C" void kernel_launch(void* const* d_in, const int* in_sizes, int n_in,
                              void* d_out, int out_size, void* d_ws, size_t ws_size,
                              hipStream_t stream) {
    (void)in_sizes; (void)n_in; (void)d_ws; (void)ws_size; (void)out_size;
    const float* x    = (const float*)d_in[0];
    const float* W_ih = (const float*)d_in[1];
    const float* W_hh = (const float*)d_in[2];
    const float* b_ih = (const float*)d_in[3];
    const float* b_hh = (const float*)d_in[4];
    const float* W_fc = (const float*)d_in[5];
    const float* b_fc = (const float*)d_in[6];
    float* out = (float*)d_out;
    hipLaunchKernelGGL(lstm_fused_kernel, dim3(kB / 16), dim3(256), 0, stream,
                       x, W_ih, W_hh, b_ih, b_hh, W_fc, b_fc, out);
}

// Round 6
// 340.495 us; speedup vs baseline: 1.1479x; 1.0352x over previous
//
#include <hip/hip_runtime.h>
#include <cstddef>

namespace {

constexpr int kB   = 4096;
constexpr int kT   = 1024;
constexpr int kI   = 8;
constexpr int kH   = 12;
constexpr int kA   = 4;
constexpr int kTC  = 32;               // timesteps per staged chunk
constexpr int kNCH = kT / kTC;         // 32 chunks
constexpr int kXRow  = kTC * kI + 8;   // 264 floats per element region
constexpr int kWaveX = 2 * kXRow;      // 528 floats per wave (2 elements)
constexpr int kBlkX  = 4 * kWaveX;     // 2112 floats per buffer (4 waves)

constexpr float kL2E  = 1.442695041f;  // log2(e)
constexpr float kL2E2 = 2.885390082f;  // 2*log2(e)

// DPP row_ror:N within 16-lane rows — VALU pipe (r5-proven).
template<int N>
__device__ __forceinline__ float ror16(float v) {
    return __int_as_float(__builtin_amdgcn_mov_dpp(__float_as_int(v), 0x120 + N, 0xF, 0xF, false));
}
__device__ __forceinline__ float bperm(int byte_addr, float v) {
    return __int_as_float(__builtin_amdgcn_ds_bpermute(byte_addr, __float_as_int(v)));
}

__global__ __launch_bounds__(256, 2)
void lstm_fused_kernel(const float* __restrict__ x,
                       const float* __restrict__ W_ih,
                       const float* __restrict__ W_hh,
                       const float* __restrict__ b_ih,
                       const float* __restrict__ b_hh,
                       const float* __restrict__ W_fc,
                       const float* __restrict__ b_fc,
                       float* __restrict__ out) {
    __shared__ float xs[2][kBlkX];     // staged x, double-buffered, wave-private regions

    const int tid = threadIdx.x;
    const int wv  = tid >> 6;          // wave in block
    const int l64 = tid & 63;          // lane in wave
    const int ri  = l64 >> 4;          // 16-row index 0..3
    const int r   = l64 & 15;          // position within row (unit index)
    const int e   = ri & 1;            // element within wave (rows 0,2: elem0; 1,3: elem1)
    const int gh  = ri >> 1;           // 0: (i,f) rows [+FC], 1: (g,o) rows
    const int b0  = blockIdx.x * 8 + wv * 2;
    const int b   = b0 + e;            // this lane's batch element
    const bool isFC = (gh == 0) && (r >= kH);
    const int a  = isFC ? (r - kH) : 0;

    // DPP row_ror direction probe (r5-proven: immune to sign convention)
    const int probe = __builtin_amdgcn_mov_dpp(r, 0x121, 0xF, 0xF, false);
    const int dir   = (probe - r) & 15;

    // ---- per-lane weights: two gate rows, h-columns pre-rotated to the DPP order ----
    float w1[16], w2[16], x1[8], x2[8], b1, b2;
    if (r < kH) {
        const int row1 = (gh == 0) ? (0 * kH + r) : (2 * kH + r);   // i or g
        const int row2 = (gh == 0) ? (1 * kH + r) : (3 * kH + r);   // f or o
#pragma unroll
        for (int k = 0; k < 16; ++k) {
            const int col = (r + dir * k) & 15;
            w1[k] = (col < kH) ? W_hh[row1 * kH + col] : 0.0f;
            w2[k] = (col < kH) ? W_hh[row2 * kH + col] : 0.0f;
        }
#pragma unroll
        for (int i = 0; i < 8; ++i) { x1[i] = W_ih[row1 * kI + i]; x2[i] = W_ih[row2 * kI + i]; }
        b1 = b_ih[row1] + b_hh[row1];
        b2 = b_ih[row2] + b_hh[row2];
    } else if (gh == 0) {              // FC lane: dot1 = W_fc row, dot2 = 0
#pragma unroll
        for (int k = 0; k < 16; ++k) {
            const int col = (r + dir * k) & 15;
            w1[k] = (col < kH) ? W_fc[a * kH + col] : 0.0f;
            w2[k] = 0.0f;
        }
#pragma unroll
        for (int i = 0; i < 8; ++i) { x1[i] = 0.0f; x2[i] = 0.0f; }
        b1 = b_fc[a]; b2 = 0.0f;
    } else {                           // (g,o)-side pad lanes: all zero
#pragma unroll
        for (int k = 0; k < 16; ++k) { w1[k] = 0.0f; w2[k] = 0.0f; }
#pragma unroll
        for (int i = 0; i < 8; ++i)  { x1[i] = 0.0f; x2[i] = 0.0f; }
        b1 = 0.0f; b2 = 0.0f;
    }
    // act1: sigmoid on (i) rows, tanh (=2*sig(2v)-1) on (g) rows; act2: sigmoid (f / o)
    const float c1 = (gh == 0) ? -kL2E : -kL2E2;
    const float m1 = (gh == 0) ? 1.0f : 2.0f;
    const float a1 = (gh == 0) ? 0.0f : -1.0f;
    const int  exa = (l64 ^ 32) << 2;   // bpermute addr: partner lane across wave halves

    // ---- x staging (wave-private, fence-ordered; r3/r4/r5-proven pattern) ----
    const float* xga = x + (size_t)b0 * (kT * kI);         // elem0
    const float* xgb = x + (size_t)(b0 + 1) * (kT * kI);   // elem1
    const int wb = wv * kWaveX;

    float4 rva, rvb;
    {   // prologue: stage chunk 0 into buffer 0
        rva = ((const float4*)xga)[l64];
        rvb = ((const float4*)xgb)[l64];
        *(float4*)&xs[0][wb + l64 * 4]         = rva;
        *(float4*)&xs[0][wb + kXRow + l64 * 4] = rvb;
    }
    asm volatile("s_waitcnt lgkmcnt(0)" ::: "memory");
    __builtin_amdgcn_sched_barrier(0);
    const int rb = wb + e * kXRow;     // this lane's element x region
    float4 xp0 = *(const float4*)&xs[0][rb];
    float4 xp1 = *(const float4*)&xs[0][rb + 4];

    float h = 0.0f, c = 0.0f;
    float hr[16];
#pragma unroll
    for (int k = 0; k < 16; ++k) hr[k] = 0.0f;

    float* op = out + (size_t)b * (kT * kA) + a;   // moving FC output ptr

    int cb = 0;
#pragma unroll 1
    for (int ch = 0; ch < kNCH; ++ch) {
        if (ch + 1 < kNCH) {   // issue next chunk's global loads early
            rva = ((const float4*)(xga + (size_t)(ch + 1) * (kTC * kI)))[l64];
            rvb = ((const float4*)(xgb + (size_t)(ch + 1) * (kTC * kI)))[l64];
        }
#pragma unroll 2
        for (int tt = 0; tt < kTC; ++tt) {
            // two gate dots over rotated h (16, zero-padded) and x (8)
            float s1 = b1, s2 = b2;
#pragma unroll
            for (int k = 0; k < 16; ++k) {
                s1 = fmaf(w1[k], hr[k], s1);
                s2 = fmaf(w2[k], hr[k], s2);
            }
            const float xv[8] = {xp0.x, xp0.y, xp0.z, xp0.w, xp1.x, xp1.y, xp1.z, xp1.w};
#pragma unroll
            for (int i = 0; i < 8; ++i) {
                s1 = fmaf(x1[i], xv[i], s1);
                s2 = fmaf(x2[i], xv[i], s2);
            }
            // prefetch next step's x (broadcast read, off critical path)
            if (tt + 1 < kTC) {
                xp0 = *(const float4*)&xs[cb][rb + (tt + 1) * 8];
                xp1 = *(const float4*)&xs[cb][rb + (tt + 1) * 8 + 4];
            }
            // FC lanes: s1 = wfc.h_{t-1} + b_fc = out[t-1] (pre-activation, delayed store)
            if ((ch | tt) != 0) { if (isFC) op[-kA] = s1; }
            // activations (per-lane constants keep the path wave-uniform)
            const float e1   = __builtin_amdgcn_exp2f(c1 * s1);
            const float act1 = fmaf(m1, __builtin_amdgcn_rcpf(1.0f + e1), a1); // sig(i)|tanh(g)
            const float e2   = __builtin_amdgcn_exp2f(-kL2E * s2);
            const float act2 = __builtin_amdgcn_rcpf(1.0f + e2);               // sig(f)|sig(o)
            // exchange with partner half (2 DS ops/step — LDS pipe stays cold)
            const float o1 = bperm(exa, act1);
            const float o2 = bperm(exa, act2);
            const float iv = (gh == 0) ? act1 : o1;
            const float fv = (gh == 0) ? act2 : o2;
            const float gv = (gh == 0) ? o1 : act1;
            const float ov = (gh == 0) ? o2 : act2;
            // state update (computed redundantly on both halves — whole-wave issue anyway)
            c = fmaf(fv, c, iv * gv);
            const float ec = __builtin_amdgcn_exp2f(-kL2E2 * c);
            const float tc = fmaf(2.0f, __builtin_amdgcn_rcpf(1.0f + ec), -1.0f);
            h = ov * tc;
            // all-gather h within each 16-row (VALU pipe)
            hr[0]  = h;
            hr[1]  = ror16<1>(h);
            hr[2]  = ror16<2>(h);
            hr[3]  = ror16<3>(h);
            hr[4]  = ror16<4>(h);
            hr[5]  = ror16<5>(h);
            hr[6]  = ror16<6>(h);
            hr[7]  = ror16<7>(h);
            hr[8]  = ror16<8>(h);
            hr[9]  = ror16<9>(h);
            hr[10] = ror16<10>(h);
            hr[11] = ror16<11>(h);
            hr[12] = ror16<12>(h);
            hr[13] = ror16<13>(h);
            hr[14] = ror16<14>(h);
            hr[15] = ror16<15>(h);
            op += kA;
        }
        if (ch + 1 < kNCH) {   // late LDS write of prefetched chunk + fence
            const int nb = cb ^ 1;
            *(float4*)&xs[nb][wb + l64 * 4]         = rva;
            *(float4*)&xs[nb][wb + kXRow + l64 * 4] = rvb;
            asm volatile("s_waitcnt lgkmcnt(0)" ::: "memory");
            __builtin_amdgcn_sched_barrier(0);
            xp0 = *(const float4*)&xs[nb][rb];
            xp1 = *(const float4*)&xs[nb][rb + 4];
            cb = nb;
        }
    }

    {   // epilogue: out[T-1] = wfc . h_{T-1} + b_fc (x-weights are zero on FC lanes)
        float s1 = b1;
#pragma unroll
        for (int k = 0; k < 16; ++k) s1 = fmaf(w1[k], hr[k], s1);
        if (isFC) op[-kA] = s1;
    }
    if (gh == 0 && r < kH) {   // hn, cn (shapes [1,B,12] each), concatenated after out
        float* hn = out + (size_t)kB * kT * kA;
        hn[(size_t)b * kH + r] = h;
        hn[(size_t)kB * kH + (size_t)b * kH + r] = c;
    }
}

}  // namespace

extern "C" void kernel_launch(void* const* d_in, const int* in_sizes, int n_in,
                              void* d_out, int out_size, void* d_ws, size_t ws_size,
                              hipStream_t stream) {
    (void)in_sizes; (void)n_in; (void)d_ws; (void)ws_size; (void)out_size;
    const float* x    = (const float*)d_in[0];
    const float* W_ih = (const float*)d_in[1];
    const float* W_hh = (const float*)d_in[2];
    const float* b_ih = (const float*)d_in[3];
    const float* b_hh = (const float*)d_in[4];
    const float* W_fc = (const float*)d_in[5];
    const float* b_fc = (const float*)d_in[6];
    float* out = (float*)d_out;
    hipLaunchKernelGGL(lstm_fused_kernel, dim3(kB / 8), dim3(256), 0, stream,
                       x, W_ih, W_hh, b_ih, b_hh, W_fc, b_fc, out);
}

// Round 7
// 298.177 us; speedup vs baseline: 1.3108x; 1.1419x over previous
//
#include <hip/hip_runtime.h>
#include <cstddef>
#include <cstdint>

namespace {

typedef __fp16 h2v __attribute__((ext_vector_type(2)));

constexpr int kB = 4096, kT = 1024, kI = 8, kH = 12, kA = 4;
constexpr int kTC = 32;               // timesteps per staged chunk
constexpr int kNCH = kT / kTC;        // 32 chunks
// LDS in uints: per element chunk = 32 steps * 8 f16 = 128 uints (512 B)
constexpr int kWaveU = 256;           // 2 elements * 128 uints per wave
constexpr int kBlkU  = 4 * kWaveU;    // 1024 uints per buffer

constexpr float kL2E  = 1.442695041f;   // log2(e)
constexpr float kL2E2 = 2.885390082f;   // 2*log2(e)

template<int N>
__device__ __forceinline__ uint32_t ror16u(uint32_t v) {
    return (uint32_t)__builtin_amdgcn_mov_dpp((int)v, 0x120 + N, 0xF, 0xF, false);
}
__device__ __forceinline__ float ror16f1(float v) {   // row_ror:1 (matches dir probe)
    return __int_as_float(__builtin_amdgcn_mov_dpp(__float_as_int(v), 0x121, 0xF, 0xF, false));
}
__device__ __forceinline__ float bperm(int byte_addr, float v) {
    return __int_as_float(__builtin_amdgcn_ds_bpermute(byte_addr, __float_as_int(v)));
}
__device__ __forceinline__ uint32_t pkrtz(float lo, float hi) {
    auto v = __builtin_amdgcn_cvt_pkrtz(lo, hi);     // v2f16 (x=lo, y=hi)
    return __builtin_bit_cast(uint32_t, v);
}
__device__ __forceinline__ h2v uh(uint32_t u) { return __builtin_bit_cast(h2v, u); }

__global__ __launch_bounds__(256, 2)
void lstm_fused_kernel(const float* __restrict__ x,
                       const float* __restrict__ W_ih,
                       const float* __restrict__ W_hh,
                       const float* __restrict__ b_ih,
                       const float* __restrict__ b_hh,
                       const float* __restrict__ W_fc,
                       const float* __restrict__ b_fc,
                       float* __restrict__ out) {
    __shared__ uint32_t xs[2][kBlkU];   // staged x (f16 pairs), double-buffered, wave-private

    const int tid = threadIdx.x;
    const int wv  = tid >> 6;           // wave in block
    const int l64 = tid & 63;           // lane in wave
    const int ri  = l64 >> 4;           // 16-row 0..3
    const int r   = l64 & 15;           // unit index within row
    const int e   = ri & 1;             // element (rows 0,2: elem0; rows 1,3: elem1)
    const int gh  = ri >> 1;            // 0: (i,f) rows [+FC], 1: (g,o) rows
    const int b0  = blockIdx.x * 8 + wv * 2;
    const int b   = b0 + e;
    const bool isFC = (gh == 0) && (r >= kH);
    const int a  = isFC ? (r - kH) : 0;

    // DPP row_ror direction probe (r5/r6-proven)
    const int probe = __builtin_amdgcn_mov_dpp(r, 0x121, 0xF, 0xF, false);
    const int dir   = (probe - r) & 15;

    // ---- packed f16 weights; h-cols pre-rotated & PAIRED to match Q-rotation ----
    // hrp[j] (lane r) = (h_c0, h_c1), c0=(r+dir*2j)&15, c1=(c0+dir)&15.
    // Gate rows pre-scaled by the exp2 activation constant (FC rows unscaled).
    h2v w1p[8], w2p[8], x1p[4], x2p[4];
    float b1, b2;
    if (r < kH) {
        const int row1 = (gh == 0) ? r : (2 * kH + r);          // i or g
        const int row2 = (gh == 0) ? (kH + r) : (3 * kH + r);   // f or o
        const float scl1 = (gh == 0) ? -kL2E : -kL2E2;
        const float scl2 = -kL2E;
#pragma unroll
        for (int j = 0; j < 8; ++j) {
            const int c0 = (r + dir * 2 * j) & 15;
            const int cc = (c0 + dir) & 15;
            const float u0 = (c0 < kH) ? W_hh[row1 * kH + c0] : 0.0f;
            const float u1 = (cc < kH) ? W_hh[row1 * kH + cc] : 0.0f;
            const float v0 = (c0 < kH) ? W_hh[row2 * kH + c0] : 0.0f;
            const float v1 = (cc < kH) ? W_hh[row2 * kH + cc] : 0.0f;
            w1p[j] = h2v{(__fp16)(scl1 * u0), (__fp16)(scl1 * u1)};
            w2p[j] = h2v{(__fp16)(scl2 * v0), (__fp16)(scl2 * v1)};
        }
#pragma unroll
        for (int i2 = 0; i2 < 4; ++i2) {
            x1p[i2] = h2v{(__fp16)(scl1 * W_ih[row1 * kI + 2 * i2]),
                          (__fp16)(scl1 * W_ih[row1 * kI + 2 * i2 + 1])};
            x2p[i2] = h2v{(__fp16)(scl2 * W_ih[row2 * kI + 2 * i2]),
                          (__fp16)(scl2 * W_ih[row2 * kI + 2 * i2 + 1])};
        }
        b1 = scl1 * (b_ih[row1] + b_hh[row1]);
        b2 = scl2 * (b_ih[row2] + b_hh[row2]);
    } else if (gh == 0) {   // FC lane: unscaled (stores s1 pre-activation)
#pragma unroll
        for (int j = 0; j < 8; ++j) {
            const int c0 = (r + dir * 2 * j) & 15;
            const int cc = (c0 + dir) & 15;
            const float u0 = (c0 < kH) ? W_fc[a * kH + c0] : 0.0f;
            const float u1 = (cc < kH) ? W_fc[a * kH + cc] : 0.0f;
            w1p[j] = h2v{(__fp16)u0, (__fp16)u1};
            w2p[j] = h2v{(__fp16)0.f, (__fp16)0.f};
        }
#pragma unroll
        for (int i2 = 0; i2 < 4; ++i2) {
            x1p[i2] = h2v{(__fp16)0.f, (__fp16)0.f};
            x2p[i2] = h2v{(__fp16)0.f, (__fp16)0.f};
        }
        b1 = b_fc[a]; b2 = 0.0f;
    } else {                // (g,o)-side pad lanes: h stays exactly 0 (proven r6)
#pragma unroll
        for (int j = 0; j < 8; ++j) { w1p[j] = h2v{(__fp16)0.f, (__fp16)0.f}; w2p[j] = w1p[j]; }
#pragma unroll
        for (int i2 = 0; i2 < 4; ++i2) { x1p[i2] = h2v{(__fp16)0.f, (__fp16)0.f}; x2p[i2] = x1p[i2]; }
        b1 = 0.0f; b2 = 0.0f;
    }
    const float m1  = (gh == 0) ? 1.0f : 2.0f;    // act1 = m1*rcp(1+exp2(s1')) + a1c
    const float a1c = (gh == 0) ? 0.0f : -1.0f;
    const int  exa  = (l64 ^ 32) << 2;            // partner lane across wave halves

    // ---- x staging: f32 global loads -> f16 pairs in LDS (wave-private, fence-ordered) ----
    const float* xga = x + (size_t)b0 * (kT * kI);
    const float* xgb = xga + (size_t)kT * kI;
    const int wbu = wv * kWaveU;
    const int rbu = wbu + e * 128;       // this lane's element region (uints)

    float4 rva = ((const float4*)xga)[l64];
    float4 rvb = ((const float4*)xgb)[l64];
    {
        uint2 ua; ua.x = pkrtz(rva.x, rva.y); ua.y = pkrtz(rva.z, rva.w);
        uint2 ub; ub.x = pkrtz(rvb.x, rvb.y); ub.y = pkrtz(rvb.z, rvb.w);
        *(uint2*)&xs[0][wbu + l64 * 2]       = ua;
        *(uint2*)&xs[0][wbu + 128 + l64 * 2] = ub;
    }
    asm volatile("s_waitcnt lgkmcnt(0)" ::: "memory");
    __builtin_amdgcn_sched_barrier(0);
    uint4 xr = *(const uint4*)&xs[0][rbu];   // step 0: 8 f16 = 4 half2

    float h = 0.0f, c = 0.0f;
    uint32_t hrp[8];
#pragma unroll
    for (int k = 0; k < 8; ++k) hrp[k] = 0u;

    float* op = out + (size_t)b * (kT * kA) + a;

    int cb = 0;
#pragma unroll 1
    for (int ch = 0; ch < kNCH; ++ch) {
        if (ch + 1 < kNCH) {   // issue next chunk's global loads early
            rva = ((const float4*)(xga + (size_t)(ch + 1) * (kTC * kI)))[l64];
            rvb = ((const float4*)(xgb + (size_t)(ch + 1) * (kTC * kI)))[l64];
        }
#pragma unroll 2
        for (int tt = 0; tt < kTC; ++tt) {
            // two gate dots: 16 fdot2 over paired h + 8 over x (fp32 accum)
            float s1 = b1, s2 = b2;
#pragma unroll
            for (int j = 0; j < 8; ++j) {
                const h2v hv = uh(hrp[j]);
                s1 = __builtin_amdgcn_fdot2(w1p[j], hv, s1, false);
                s2 = __builtin_amdgcn_fdot2(w2p[j], hv, s2, false);
            }
            s1 = __builtin_amdgcn_fdot2(x1p[0], uh(xr.x), s1, false);
            s2 = __builtin_amdgcn_fdot2(x2p[0], uh(xr.x), s2, false);
            s1 = __builtin_amdgcn_fdot2(x1p[1], uh(xr.y), s1, false);
            s2 = __builtin_amdgcn_fdot2(x2p[1], uh(xr.y), s2, false);
            s1 = __builtin_amdgcn_fdot2(x1p[2], uh(xr.z), s1, false);
            s2 = __builtin_amdgcn_fdot2(x2p[2], uh(xr.z), s2, false);
            s1 = __builtin_amdgcn_fdot2(x1p[3], uh(xr.w), s1, false);
            s2 = __builtin_amdgcn_fdot2(x2p[3], uh(xr.w), s2, false);
            // prefetch next step's x (broadcast read, off critical path)
            if (tt + 1 < kTC) xr = *(const uint4*)&xs[cb][rbu + (tt + 1) * 4];
            // FC lanes: s1 = wfc.h_{t-1} + b_fc = out[t-1] (delayed store)
            if ((ch | tt) != 0) { if (isFC) op[-kA] = s1; }
            // activations (scale pre-folded into weights)
            const float e1   = __builtin_amdgcn_exp2f(s1);
            const float act1 = fmaf(m1, __builtin_amdgcn_rcpf(1.0f + e1), a1c); // sig(i)|tanh(g)
            const float e2   = __builtin_amdgcn_exp2f(s2);
            const float act2 = __builtin_amdgcn_rcpf(1.0f + e2);                // sig(f)|sig(o)
            // exchange with partner half (2 DS ops/step)
            const float o1 = bperm(exa, act1);
            const float o2 = bperm(exa, act2);
            const float fv = (gh == 0) ? act2 : o2;
            const float ov = (gh == 0) ? o2 : act2;
            // state update (i*g = act1*o1 on BOTH halves — no select needed)
            c = fmaf(fv, c, act1 * o1);
            const float ec = __builtin_amdgcn_exp2f(-kL2E2 * c);
            const float tc = fmaf(2.0f, __builtin_amdgcn_rcpf(1.0f + ec), -1.0f);
            h = ov * tc;
            // packed h broadcast: Q = (h_r, h_{r+dir}); one DPP rotate = two h values
            const float hn1 = ror16f1(h);
            const uint32_t Q = pkrtz(h, hn1);
            hrp[0] = Q;
            hrp[1] = ror16u<2>(Q);
            hrp[2] = ror16u<4>(Q);
            hrp[3] = ror16u<6>(Q);
            hrp[4] = ror16u<8>(Q);
            hrp[5] = ror16u<10>(Q);
            hrp[6] = ror16u<12>(Q);
            hrp[7] = ror16u<14>(Q);
            op += kA;
        }
        if (ch + 1 < kNCH) {   // late LDS write of prefetched chunk + fence
            const int nb = cb ^ 1;
            uint2 ua; ua.x = pkrtz(rva.x, rva.y); ua.y = pkrtz(rva.z, rva.w);
            uint2 ub; ub.x = pkrtz(rvb.x, rvb.y); ub.y = pkrtz(rvb.z, rvb.w);
            *(uint2*)&xs[nb][wbu + l64 * 2]       = ua;
            *(uint2*)&xs[nb][wbu + 128 + l64 * 2] = ub;
            asm volatile("s_waitcnt lgkmcnt(0)" ::: "memory");
            __builtin_amdgcn_sched_barrier(0);
            xr = *(const uint4*)&xs[nb][rbu];
            cb = nb;
        }
    }

    {   // epilogue: out[T-1] = wfc . h_{T-1} + b_fc
        float s1 = b1;
#pragma unroll
        for (int j = 0; j < 8; ++j)
            s1 = __builtin_amdgcn_fdot2(w1p[j], uh(hrp[j]), s1, false);
        if (isFC) op[-kA] = s1;
    }
    if (gh == 0 && r < kH) {   // hn, cn (fp32 master state)
        float* hn = out + (size_t)kB * kT * kA;
        hn[(size_t)b * kH + r] = h;
        hn[(size_t)kB * kH + (size_t)b * kH + r] = c;
    }
}

}  // namespace

extern "C" void kernel_launch(void* const* d_in, const int* in_sizes, int n_in,
                              void* d_out, int out_size, void* d_ws, size_t ws_size,
                              hipStream_t stream) {
    (void)in_sizes; (void)n_in; (void)d_ws; (void)ws_size; (void)out_size;
    const float* x    = (const float*)d_in[0];
    const float* W_ih = (const float*)d_in[1];
    const float* W_hh = (const float*)d_in[2];
    const float* b_ih = (const float*)d_in[3];
    const float* b_hh = (const float*)d_in[4];
    const float* W_fc = (const float*)d_in[5];
    const float* b_fc = (const float*)d_in[6];
    float* out = (float*)d_out;
    hipLaunchKernelGGL(lstm_fused_kernel, dim3(kB / 8), dim3(256), 0, stream,
                       x, W_ih, W_hh, b_ih, b_hh, W_fc, b_fc, out);
}